// Round 5
// baseline (395.361 us; speedup 1.0000x reference)
//
#include <hip/hip_runtime.h>
#include <math.h>

// B=2, H=W=64, N=4096, C=128, K=8, 5 Sinkhorn iters.
// Workspace holds E0 = exp(S) (fp32, selection-safe); duals kept as w=e^v, z=e^u.
#define UVS 4104   // padded dual-array batch stride (float4-aligned)

// Workspace layout (float offsets); ws is 256 MiB, we use ~153 MB.
#define OFF_ZU    33554432ul               // 2*4096*4096 floats of E0 first
#define OFF_WV    (OFF_ZU + 2*UVS)
#define OFF_RN    (OFF_WV + 2*UVS)         // 16384 (rnA | rnB)
#define OFF_PARTS (OFF_RN + 16384)         // 2*512*4096 col partials / bf16 pack (time-shared)
#define OFF_TKV   (OFF_PARTS + 4194304)    // 2*4096*8
#define OFF_TKP   (OFF_TKV + 65536)        // 2*4096*8*2
#define OFF_DP    (OFF_TKP + 131072)       // 2*8*2*4096 planar
#define OFF_GEO   (OFF_DP + 131072)        // 2*4096*8
#define OFF_SUM   (OFF_GEO + 65536)        // 24 doubles

#define EXPC    0.0001220703125f           // e^NORMC = 1/8192
#define HALFC   0.5f                       // e^{log(N)+NORMC} = 1/2

#define PLANE   1048576                    // shorts per pack plane: 2*256*16*16*8

typedef __attribute__((ext_vector_type(8))) short bf16x8;
typedef __attribute__((ext_vector_type(4))) float f32x4;

static __device__ __forceinline__ unsigned f2bf(float x) {  // RTNE fp32->bf16 bits
    unsigned u = __float_as_uint(x);
    return (u + 0x7FFFu + ((u >> 16) & 1u)) >> 16;
}
static __device__ __forceinline__ float bf2f(unsigned h) { return __uint_as_float(h << 16); }

// --- 0) init duals: w = e^0 = 1 everywhere (incl. dustbin) ---
__global__ __launch_bounds__(256) void init_kernel(float* __restrict__ wv)
{
    int i = blockIdx.x * 256 + threadIdx.x;
    if (i < 2 * UVS) wv[i] = 1.0f;
}

// --- 1) inverse L2 norms ---
__global__ __launch_bounds__(256) void norms_kernel(
    const float* __restrict__ fA, const float* __restrict__ fB, float* __restrict__ rn)
{
    int t = threadIdx.x;
    int rowg = blockIdx.x * 4 + (t >> 6);
    int lane = t & 63;
    const float* f = (rowg < 8192) ? fA : fB;
    int r = rowg & 8191;
    float x0 = f[(size_t)r * 128 + lane];
    float x1 = f[(size_t)r * 128 + 64 + lane];
    float s = x0 * x0 + x1 * x1;
    #pragma unroll
    for (int off = 32; off > 0; off >>= 1) s += __shfl_xor(s, off, 64);
    if (lane == 0) rn[rowg] = 1.f / fmaxf(sqrtf(s), 1e-12f);
}

// --- 1b) one-time fp32 -> hi/lo bf16 conversion, fragment-major layout ---
__global__ __launch_bounds__(256) void pack_kernel(
    const float* __restrict__ fA, const float* __restrict__ fB, short* __restrict__ pk)
{
    int gt = blockIdx.x * 256 + threadIdx.x;   // 0..262143
    int tensor = gt >> 17;                      // 0 = A, 1 = B
    int t = gt & 131071;                        // (b, rb, kc, fr)
    int fr = t & 15;
    int kc = (t >> 4) & 15;
    int rb = (t >> 8) & 255;
    int b  = t >> 16;
    const float* src = tensor ? fB : fA;
    const float* p = src + ((size_t)(b * 4096 + rb * 16 + fr)) * 128 + kc * 8;
    float4 v0 = *(const float4*)p;
    float4 v1 = *(const float4*)(p + 4);
    float el[8] = {v0.x, v0.y, v0.z, v0.w, v1.x, v1.y, v1.z, v1.w};
    unsigned h[8], l[8];
    #pragma unroll
    for (int e = 0; e < 8; e++) { h[e] = f2bf(el[e]); l[e] = f2bf(el[e] - bf2f(h[e])); }
    uint4 hw = make_uint4(h[0] | (h[1] << 16), h[2] | (h[3] << 16),
                          h[4] | (h[5] << 16), h[6] | (h[7] << 16));
    uint4 lw = make_uint4(l[0] | (l[1] << 16), l[2] | (l[3] << 16),
                          l[4] | (l[5] << 16), l[6] | (l[7] << 16));
    size_t off = ((size_t)(b * 256 + rb)) * 2048 + kc * 128 + fr * 8;
    short* hi = pk + (size_t)tensor * 2 * PLANE;
    *(uint4*)(hi + off) = hw;
    *(uint4*)(hi + PLANE + off) = lw;
}

// --- 2) E0 = exp((fA.fB^T)*rnA*rnB/temp), pre-packed bf16 hi/lo MFMA ---
__global__ __launch_bounds__(256) void gemm_mfma(
    const short* __restrict__ pk, const float* __restrict__ rn,
    const float* __restrict__ temp, float* __restrict__ E0)
{
    __shared__ short Bs[16384];    // [hi|lo][nb=4][kchunk=16][fr=16][8] = 32 KB
    int b = blockIdx.z;
    int i0 = blockIdx.y * 64, j0 = blockIdx.x * 64;
    int t = threadIdx.x;
    int wave = t >> 6, lane = t & 63;
    int fr = lane & 15;
    int quad = lane >> 4;

    // stage B panel (4 consecutive rowblks = contiguous 16 KB per plane)
    const short* gBhi = pk + 2 * (size_t)PLANE + ((size_t)(b * 256 + (j0 >> 4))) * 2048;
    const short* gBlo = gBhi + PLANE;
    #pragma unroll
    for (int c = 0; c < 4; c++) {
        int ch = c * 256 + t;                       // 0..1023 16B-chunks
        *(uint4*)&Bs[ch * 8]        = *(const uint4*)(gBhi + ch * 8);
        *(uint4*)&Bs[8192 + ch * 8] = *(const uint4*)(gBlo + ch * 8);
    }

    // A fragments for this wave's 16 rows: 8 coalesced 16B loads per lane
    const short* Abase_hi = pk + ((size_t)(b * 256 + (i0 >> 4) + wave)) * 2048;
    const short* Abase_lo = Abase_hi + PLANE;
    bf16x8 ah[4], al[4];
    #pragma unroll
    for (int s = 0; s < 4; s++) {
        ah[s] = *(const bf16x8*)(Abase_hi + s * 512 + lane * 8);
        al[s] = *(const bf16x8*)(Abase_lo + s * 512 + lane * 8);
    }
    __syncthreads();

    f32x4 acc[4] = {f32x4{0,0,0,0}, f32x4{0,0,0,0}, f32x4{0,0,0,0}, f32x4{0,0,0,0}};
    #pragma unroll
    for (int s = 0; s < 4; s++) {                   // k-step = 32 (kchunks s*4..s*4+3)
        int lo = s * 512 + lane * 8;
        #pragma unroll
        for (int nb = 0; nb < 4; nb++) {
            bf16x8 bh = *(const bf16x8*)&Bs[nb * 2048 + lo];
            bf16x8 bl = *(const bf16x8*)&Bs[8192 + nb * 2048 + lo];
            acc[nb] = __builtin_amdgcn_mfma_f32_16x16x32_bf16(ah[s], bh, acc[nb], 0, 0, 0);
            acc[nb] = __builtin_amdgcn_mfma_f32_16x16x32_bf16(al[s], bh, acc[nb], 0, 0, 0);
            acc[nb] = __builtin_amdgcn_mfma_f32_16x16x32_bf16(ah[s], bl, acc[nb], 0, 0, 0);
        }
    }

    float invt = 1.f / temp[0];
    int m0 = i0 + wave * 16 + quad * 4;
    float ra[4];
    #pragma unroll
    for (int rr = 0; rr < 4; rr++) ra[rr] = rn[b * 4096 + m0 + rr] * invt;
    #pragma unroll
    for (int nb = 0; nb < 4; nb++) {
        int col = j0 + nb * 16 + fr;
        float rbv = rn[8192 + b * 4096 + col];
        #pragma unroll
        for (int rr = 0; rr < 4; rr++)
            E0[((size_t)(b * 4096 + m0 + rr)) * 4096 + col] = __expf(acc[nb][rr] * (ra[rr] * rbv));
    }
}

// --- 3) fused Sinkhorn iteration: ONE WAVE PER 8-ROW CHUNK, zero LDS ---
// grid (512,1,2), block 64 = 1 wave -> 1024 blocks, 4/CU, ALL 256 CUs active
// (round-4 version used 128 blocks = half the machine; active CUs were at the
// per-CU HBM ceiling, so doubling CU coverage should ~halve duration).
// parts stores the UNSCALED colsum  A_j = sum_i E0_ij * z_i over 512 slices.
__global__ __launch_bounds__(64) void sink_fused(
    const float* __restrict__ E0, float* __restrict__ zu, const float* __restrict__ wv,
    const float* __restrict__ dbp, float* __restrict__ parts)
{
    int b = blockIdx.z;
    int lane = threadIdx.x;                        // 0..63
    int ch = blockIdx.x;                           // 0..511 (8 rows each)
    const float* wb = wv + b * UVS;
    float edb = __expf(dbp[0]);

    // chunk 0 refreshes the dustbin-row dual: zuN = 0.5/(e^db*sum_j w_j + w_N)
    if (ch == 0) {
        float sv = 0.f;
        #pragma unroll
        for (int c = 0; c < 16; c++) {
            f32x4 w4 = *(const f32x4*)(wb + lane * 4 + c * 256);
            sv += (w4.x + w4.y) + (w4.z + w4.w);
        }
        #pragma unroll
        for (int off = 32; off > 0; off >>= 1) sv += __shfl_xor(sv, off, 64);
        if (lane == 0) zu[b * UVS + 4096] = HALFC / (edb * sv + wb[4096]);
    }

    float dtail = edb * wb[4096];
    f32x4 cacc[16];
    #pragma unroll
    for (int c = 0; c < 16; c++) cacc[c] = f32x4{0, 0, 0, 0};

    const float* Eb = E0 + ((size_t)b << 24);
    int base = lane * 4;

    for (int r = 0; r < 8; r++) {
        int row = ch * 8 + r;
        const float* Erow = Eb + ((size_t)row << 12);
        f32x4 x4[16];
        #pragma unroll
        for (int c = 0; c < 16; c++) x4[c] = *(const f32x4*)(Erow + base + c * 256);
        f32x4 rs4 = f32x4{0, 0, 0, 0};
        #pragma unroll
        for (int c = 0; c < 16; c++) {
            f32x4 w4 = *(const f32x4*)(wb + base + c * 256);
            rs4 += x4[c] * w4;
        }
        float rs = (rs4.x + rs4.y) + (rs4.z + rs4.w);
        #pragma unroll
        for (int off = 32; off > 0; off >>= 1) rs += __shfl_xor(rs, off, 64);
        float zi = EXPC / (rs + dtail);             // identical on all lanes
        if (lane == 0) zu[b * UVS + row] = zi;
        #pragma unroll
        for (int c = 0; c < 16; c++) cacc[c] += x4[c] * zi;
    }

    float* pp = parts + ((size_t)(b * 512 + ch)) * 4096;
    #pragma unroll
    for (int c = 0; c < 16; c++) *(f32x4*)(pp + base + c * 256) = cacc[c];
}

// --- 3b) combine column partials -> w_new[j]; block 16 handles dustbin column ---
// parts is the unscaled colsum A_j = sum_i E0_ij z_i (512 slices per batch).
__global__ __launch_bounds__(256) void sink_vB(
    const float* __restrict__ parts, const float* __restrict__ zu,
    float* __restrict__ wv, const float* __restrict__ dbp)
{
    int b = blockIdx.z;
    int t = threadIdx.x;
    float edb = __expf(dbp[0]);
    if (blockIdx.x < 16) {
        int j = blockIdx.x * 256 + t;
        float s = 0.f;
        #pragma unroll 16
        for (int ch = 0; ch < 512; ch++) s += parts[((size_t)(b * 512 + ch)) * 4096 + j];
        float total = s + edb * zu[b * UVS + 4096];   // + dustbin row
        wv[b * UVS + j] = EXPC / total;               // w = e^{v_new}
    } else {
        __shared__ float red[256];
        float s = 0.f;
        for (int i = t; i < 4096; i += 256) s += zu[b * UVS + i];
        red[t] = s; __syncthreads();
        for (int off = 128; off > 0; off >>= 1) {
            if (t < off) red[t] += red[t + off];
            __syncthreads();
        }
        if (t == 0)
            wv[b * UVS + 4096] = HALFC / (edb * red[0] + zu[b * UVS + 4096]);
    }
}

// --- 4) per-row top-8 of E0*w: wave-per-row, med3 network + threshold + rank ---
// Pass 1: per-lane sorted top-8 via fmed3 insertion; q cached in 64 VGPRs so
// pass 2 is register-only (no HBM re-read). f32 butterfly -> exact t8.
// Pass 2: register rescan vs t8, push exact u64 keys to a per-wave LDS pool.
// Final: rank select over the pool (exact lax.top_k semantics: desc value,
// lowest index on ties via key = value_bits<<32 | 4095-j).
#define FCMPSWAP(a, b) { float _mx = fmaxf(a, b), _mn = fminf(a, b); (a) = _mx; (b) = _mn; }
__global__ __launch_bounds__(256) void topk_kernel(
    const float* __restrict__ E0, const float* __restrict__ zu, const float* __restrict__ wv,
    const float* __restrict__ posA, const float* __restrict__ posB,
    float* __restrict__ tkv, float* __restrict__ tkp, float* __restrict__ dp)
{
    int wave = threadIdx.x >> 6;
    int lane = threadIdx.x & 63;
    int row = blockIdx.x * 4 + wave;                 // 0..8191 == b*4096+i
    int b = row >> 12; int i = row & 4095;
    const float* Erow = E0 + (size_t)row * 4096;
    const float* wb = wv + b * UVS;

    __shared__ unsigned long long cand[4][64];
    __shared__ int ccnt[4];
    if (lane == 0) ccnt[wave] = 0;

    // pass 1: cache q in registers, branchless per-lane sorted top-8 (med3)
    f32x4 q[16];
    float s[8] = {0, 0, 0, 0, 0, 0, 0, 0};
    #pragma unroll
    for (int c = 0; c < 16; c++) {
        int j = c * 256 + lane * 4;
        f32x4 x = *(const f32x4*)(Erow + j);
        f32x4 w = *(const f32x4*)(wb + j);
        q[c] = x * w;
        float el[4] = {q[c].x, q[c].y, q[c].z, q[c].w};
        #pragma unroll
        for (int e = 0; e < 4; e++) {
            float xv = el[e];
            s[7] = __builtin_amdgcn_fmed3f(s[6], s[7], xv);
            s[6] = __builtin_amdgcn_fmed3f(s[5], s[6], xv);
            s[5] = __builtin_amdgcn_fmed3f(s[4], s[5], xv);
            s[4] = __builtin_amdgcn_fmed3f(s[3], s[4], xv);
            s[3] = __builtin_amdgcn_fmed3f(s[2], s[3], xv);
            s[2] = __builtin_amdgcn_fmed3f(s[1], s[2], xv);
            s[1] = __builtin_amdgcn_fmed3f(s[0], s[1], xv);
            s[0] = fmaxf(s[0], xv);
        }
    }

    // f32 butterfly merge: all lanes end with the row's sorted top-8 values
    #pragma unroll
    for (int st = 0; st < 6; st++) {
        int off = 1 << st;
        float o[8];
        #pragma unroll
        for (int r = 0; r < 8; r++) o[r] = __shfl_xor(s[r], off, 64);
        float m[8];
        #pragma unroll
        for (int r = 0; r < 8; r++) m[r] = fmaxf(s[r], o[7 - r]);   // bitonic union top-8
        FCMPSWAP(m[0], m[4]); FCMPSWAP(m[1], m[5]); FCMPSWAP(m[2], m[6]); FCMPSWAP(m[3], m[7]);
        FCMPSWAP(m[0], m[2]); FCMPSWAP(m[1], m[3]); FCMPSWAP(m[4], m[6]); FCMPSWAP(m[5], m[7]);
        FCMPSWAP(m[0], m[1]); FCMPSWAP(m[2], m[3]); FCMPSWAP(m[4], m[5]); FCMPSWAP(m[6], m[7]);
        #pragma unroll
        for (int r = 0; r < 8; r++) s[r] = m[r];
    }
    float t8 = s[7];                                 // true 8th-largest value

    __syncthreads();                                 // ccnt init visible

    // pass 2: register rescan vs threshold; push exact keys (rare: ~8/row)
    #pragma unroll
    for (int c = 0; c < 16; c++) {
        float el[4] = {q[c].x, q[c].y, q[c].z, q[c].w};
        #pragma unroll
        for (int e = 0; e < 4; e++) {
            if (el[e] >= t8) {
                int j = c * 256 + lane * 4 + e;
                unsigned long long key =
                    ((unsigned long long)__float_as_uint(el[e]) << 32) | (unsigned)(4095 - j);
                int slot = atomicAdd(&ccnt[wave], 1);
                if (slot < 64) cand[wave][slot] = key;
            }
        }
    }
    __syncthreads();

    // rank select over the pool (cnt >= 8 guaranteed; keys distinct via index)
    int cnt = ccnt[wave]; if (cnt > 64) cnt = 64;
    if (lane < cnt) {
        unsigned long long my = cand[wave][lane];
        int rank = 0;
        for (int j2 = 0; j2 < cnt; j2++) rank += (cand[wave][j2] > my) ? 1 : 0;
        if (rank < 8) {
            int idx = 4095 - (int)(my & 0xFFFFFFFFu);
            float candv = __uint_as_float((unsigned)(my >> 32));
            float val = candv * zu[b * UVS + i];     // p = E0*w*z
            float px = posB[((size_t)(b * 4096 + idx)) * 2 + 0];
            float py = posB[((size_t)(b * 4096 + idx)) * 2 + 1];
            float ax = posA[((size_t)(b * 4096 + i)) * 2 + 0];
            float ay = posA[((size_t)(b * 4096 + i)) * 2 + 1];
            size_t base = ((size_t)(b * 4096 + i)) * 8 + rank;
            tkv[base] = val;
            tkp[base * 2 + 0] = px; tkp[base * 2 + 1] = py;
            dp[((size_t)((b * 8 + rank) * 2 + 0)) * 4096 + i] = px - ax;
            dp[((size_t)((b * 8 + rank) * 2 + 1)) * 4096 + i] = py - ay;
        }
    }
}

// --- 5) geo: 7x7 windowed variance (count_include_pad=False) ---
__global__ __launch_bounds__(256) void geo_kernel(
    const float* __restrict__ dp, float* __restrict__ geo)
{
    int tid = blockIdx.x * 256 + threadIdx.x;   // 65536
    int n = tid & 4095; int bk = tid >> 12;
    int b = bk >> 3; int k = bk & 7;
    int h = n >> 6, w = n & 63;
    const float* dpx = dp + ((size_t)(bk * 2 + 0)) * 4096;
    const float* dpy = dp + ((size_t)(bk * 2 + 1)) * 4096;
    float sx = 0, sy = 0, sxx = 0, syy = 0, cnt = 0;
    #pragma unroll
    for (int dy = -3; dy <= 3; dy++) {
        int hh = h + dy; if ((unsigned)hh >= 64u) continue;
        #pragma unroll
        for (int dx = -3; dx <= 3; dx++) {
            int ww = w + dx; if ((unsigned)ww >= 64u) continue;
            int nn = (hh << 6) + ww;
            float vx = dpx[nn], vy = dpy[nn];
            sx += vx; sy += vy; sxx += vx * vx; syy += vy * vy; cnt += 1.f;
        }
    }
    float inv = 1.f / cnt;
    float mx = sx * inv, my = sy * inv;
    float varx = fmaxf(sxx * inv - mx * mx, 0.f);
    float vary = fmaxf(syy * inv - my * my, 0.f);
    geo[((size_t)(b * 4096 + n)) * 8 + k] = 1.f / (1.f + 100.f * (varx + vary));
}

// --- 6) softmax refine -> refined_warp + conf ---
__global__ __launch_bounds__(256) void refine_kernel(
    const float* __restrict__ tkv, const float* __restrict__ geo,
    const float* __restrict__ tkp, const float* __restrict__ gwp,
    const float* __restrict__ tpp, float* __restrict__ out)
{
    int tid = blockIdx.x * 256 + threadIdx.x;   // 0..8191
    float gw = fminf(fmaxf(gwp[0], 0.f), 2.f);
    float invt = 1.f / tpp[0];
    size_t base = (size_t)tid * 8;
    float cb[8], vv[8];
    float mx = -INFINITY;
    #pragma unroll
    for (int k = 0; k < 8; k++) { vv[k] = tkv[base + k]; cb[k] = vv[k] + gw * geo[base + k]; mx = fmaxf(mx, cb[k]); }
    float e[8], se = 0;
    #pragma unroll
    for (int k = 0; k < 8; k++) { e[k] = __expf((cb[k] - mx) * invt); se += e[k]; }
    float wx = 0, wy = 0, cf = 0; float inv = 1.f / se;
    #pragma unroll
    for (int k = 0; k < 8; k++) {
        float s = e[k] * inv;
        wx += s * tkp[(base + k) * 2 + 0];
        wy += s * tkp[(base + k) * 2 + 1];
        cf += s * vv[k];
    }
    out[(size_t)tid * 2 + 0] = wx;
    out[(size_t)tid * 2 + 1] = wy;
    out[16384 + tid] = cf;
}

// --- 7) weighted affine: 12 sums per batch (double) ---
__global__ __launch_bounds__(256) void affine_reduce(
    const float* __restrict__ posA, const float* __restrict__ out, double* __restrict__ sums)
{
    int b = blockIdx.x; int t = threadIdx.x;
    double acc[12] = {0,0,0,0,0,0,0,0,0,0,0,0};
    for (int n = t; n < 4096; n += 256) {
        size_t idx = (size_t)b * 4096 + n;
        float x = posA[idx * 2], y = posA[idx * 2 + 1];
        float dx = out[idx * 2], dy = out[idx * 2 + 1];
        float c = out[16384 + idx];
        double cd = (double)c;
        double cx = cd * x, cy = cd * y;
        acc[0] += cx * x;  acc[1] += cx * y;  acc[2] += cy * y;
        acc[3] += cx;      acc[4] += cy;      acc[5] += cd;
        acc[6] += cx * dx; acc[7] += cy * dx; acc[8] += cd * dx;
        acc[9] += cx * dy; acc[10] += cy * dy; acc[11] += cd * dy;
    }
    __shared__ double red[256];
    for (int s = 0; s < 12; s++) {
        red[t] = acc[s]; __syncthreads();
        for (int off = 128; off > 0; off >>= 1) {
            if (t < off) red[t] += red[t + off];
            __syncthreads();
        }
        if (t == 0) sums[b * 12 + s] = red[0];
        __syncthreads();
    }
}

// --- 8) closed-form 3x3 solve (AtWA block-diagonal) ---
__global__ void affine_solve(const double* __restrict__ sums, float* __restrict__ out)
{
    int t = threadIdx.x;
    if (t >= 2) return;
    int b = t;
    const double* s = sums + b * 12;
    double den = s[5] > 1e-6 ? s[5] : 1e-6;
    double g00 = s[0] / den + 1e-4, g01 = s[1] / den, g02 = s[3] / den;
    double g11 = s[2] / den + 1e-4, g12 = s[4] / den;
    double g22 = s[5] / den + 1e-4;
    double bx0 = s[6] / den, bx1 = s[7] / den, bx2 = s[8] / den;
    double by0 = s[9] / den, by1 = s[10] / den, by2 = s[11] / den;
    double c00 = g11 * g22 - g12 * g12;
    double c01 = g02 * g12 - g01 * g22;
    double c02 = g01 * g12 - g02 * g11;
    double det = g00 * c00 + g01 * c01 + g02 * c02;
    double id = 1.0 / det;
    double i00 = c00 * id, i01 = c01 * id, i02 = c02 * id;
    double i11 = (g00 * g22 - g02 * g02) * id, i12 = (g01 * g02 - g00 * g12) * id;
    double i22 = (g00 * g11 - g01 * g01) * id;
    double a_ = i00 * bx0 + i01 * bx1 + i02 * bx2;
    double b_ = i01 * bx0 + i11 * bx1 + i12 * bx2;
    double c_ = i02 * bx0 + i12 * bx1 + i22 * bx2;
    double d_ = i00 * by0 + i01 * by1 + i02 * by2;
    double e_ = i01 * by0 + i11 * by1 + i12 * by2;
    double f_ = i02 * by0 + i12 * by1 + i22 * by2;
    float* o = out + 24576 + b * 9;
    o[0] = (float)a_; o[1] = (float)b_; o[2] = (float)c_;
    o[3] = (float)d_; o[4] = (float)e_; o[5] = (float)f_;
    o[6] = 0.f; o[7] = 0.f; o[8] = 1.f;
}

extern "C" void kernel_launch(void* const* d_in, const int* in_sizes, int n_in,
                              void* d_out, int out_size, void* d_ws, size_t ws_size,
                              hipStream_t stream) {
    const float* fA = (const float*)d_in[0];
    const float* fB = (const float*)d_in[1];
    const float* pA = (const float*)d_in[2];
    const float* pB = (const float*)d_in[3];
    const float* db = (const float*)d_in[4];
    const float* gw = (const float*)d_in[5];
    const float* tp = (const float*)d_in[6];

    float* ws    = (float*)d_ws;
    float* out   = (float*)d_out;
    float* E0    = ws;
    float* zu    = ws + OFF_ZU;
    float* wv    = ws + OFF_WV;
    float* rn    = ws + OFF_RN;
    float* parts = ws + OFF_PARTS;
    short* pk    = (short*)(ws + OFF_PARTS);   // pack planes live in parts (time-shared)
    float* tkv   = ws + OFF_TKV;
    float* tkp   = ws + OFF_TKP;
    float* dp    = ws + OFF_DP;
    float* geo   = ws + OFF_GEO;
    double* sums = (double*)(ws + OFF_SUM);

    init_kernel<<<33, 256, 0, stream>>>(wv);                 // w = e^0 = 1
    norms_kernel<<<4096, 256, 0, stream>>>(fA, fB, rn);
    pack_kernel<<<1024, 256, 0, stream>>>(fA, fB, pk);
    gemm_mfma<<<dim3(64, 64, 2), 256, 0, stream>>>(pk, rn, tp, E0);

    for (int it = 0; it < 5; it++) {
        sink_fused<<<dim3(512, 1, 2), 64, 0, stream>>>(E0, zu, wv, db, parts);
        sink_vB<<<dim3(17, 1, 2), 256, 0, stream>>>(parts, zu, wv, db);
    }

    topk_kernel<<<2048, 256, 0, stream>>>(E0, zu, wv, pA, pB, tkv, tkp, dp);
    geo_kernel<<<256, 256, 0, stream>>>(dp, geo);
    refine_kernel<<<32, 256, 0, stream>>>(tkv, geo, tkp, gw, tp, out);
    affine_reduce<<<2, 256, 0, stream>>>(pA, out, sums);
    affine_solve<<<1, 64, 0, stream>>>(sums, out);
}

// Round 7
// 323.256 us; speedup vs baseline: 1.2231x; 1.2231x over previous
//
#include <hip/hip_runtime.h>
#include <math.h>

// B=2, H=W=64, N=4096, C=128, K=8, 5 Sinkhorn iters.
// Workspace holds E0 = exp(S) (fp32, selection-safe); duals kept as w=e^v, z=e^u.
#define UVS 4104   // padded dual-array batch stride (float4-aligned)

// Workspace layout (float offsets)
#define OFF_ZU    33554432ul               // 2*4096*4096 floats of E0 first
#define OFF_WV    (OFF_ZU + 2*UVS)
#define OFF_RN    (OFF_WV + 2*UVS)         // 16384 (rnA | rnB)
#define OFF_PARTS (OFF_RN + 16384)         // 2*256*4096 col partials / bf16 pack (time-shared)
#define OFF_TKV   (OFF_PARTS + 2097152)    // 2*4096*8
#define OFF_TKP   (OFF_TKV + 65536)        // 2*4096*8*2
#define OFF_DP    (OFF_TKP + 131072)       // 2*8*2*4096 planar
#define OFF_GEO   (OFF_DP + 131072)        // 2*4096*8
#define OFF_SUM   (OFF_GEO + 65536)        // 24 doubles

#define EXPC    0.0001220703125f           // e^NORMC = 1/8192
#define HALFC   0.5f                       // e^{log(N)+NORMC} = 1/2

#define PLANE   1048576                    // shorts per pack plane: 2*256*16*16*8

typedef __attribute__((ext_vector_type(8))) short bf16x8;
typedef __attribute__((ext_vector_type(4))) float f32x4;

static __device__ __forceinline__ unsigned f2bf(float x) {  // RTNE fp32->bf16 bits
    unsigned u = __float_as_uint(x);
    return (u + 0x7FFFu + ((u >> 16) & 1u)) >> 16;
}
static __device__ __forceinline__ float bf2f(unsigned h) { return __uint_as_float(h << 16); }

// --- 0) init duals: w = e^0 = 1 everywhere (incl. dustbin) ---
__global__ __launch_bounds__(256) void init_kernel(float* __restrict__ wv)
{
    int i = blockIdx.x * 256 + threadIdx.x;
    if (i < 2 * UVS) wv[i] = 1.0f;
}

// --- 1) inverse L2 norms ---
__global__ __launch_bounds__(256) void norms_kernel(
    const float* __restrict__ fA, const float* __restrict__ fB, float* __restrict__ rn)
{
    int t = threadIdx.x;
    int rowg = blockIdx.x * 4 + (t >> 6);
    int lane = t & 63;
    const float* f = (rowg < 8192) ? fA : fB;
    int r = rowg & 8191;
    float x0 = f[(size_t)r * 128 + lane];
    float x1 = f[(size_t)r * 128 + 64 + lane];
    float s = x0 * x0 + x1 * x1;
    #pragma unroll
    for (int off = 32; off > 0; off >>= 1) s += __shfl_xor(s, off, 64);
    if (lane == 0) rn[rowg] = 1.f / fmaxf(sqrtf(s), 1e-12f);
}

// --- 1b) one-time fp32 -> hi/lo bf16 conversion, fragment-major layout ---
__global__ __launch_bounds__(256) void pack_kernel(
    const float* __restrict__ fA, const float* __restrict__ fB, short* __restrict__ pk)
{
    int gt = blockIdx.x * 256 + threadIdx.x;   // 0..262143
    int tensor = gt >> 17;                      // 0 = A, 1 = B
    int t = gt & 131071;                        // (b, rb, kc, fr)
    int fr = t & 15;
    int kc = (t >> 4) & 15;
    int rb = (t >> 8) & 255;
    int b  = t >> 16;
    const float* src = tensor ? fB : fA;
    const float* p = src + ((size_t)(b * 4096 + rb * 16 + fr)) * 128 + kc * 8;
    float4 v0 = *(const float4*)p;
    float4 v1 = *(const float4*)(p + 4);
    float el[8] = {v0.x, v0.y, v0.z, v0.w, v1.x, v1.y, v1.z, v1.w};
    unsigned h[8], l[8];
    #pragma unroll
    for (int e = 0; e < 8; e++) { h[e] = f2bf(el[e]); l[e] = f2bf(el[e] - bf2f(h[e])); }
    uint4 hw = make_uint4(h[0] | (h[1] << 16), h[2] | (h[3] << 16),
                          h[4] | (h[5] << 16), h[6] | (h[7] << 16));
    uint4 lw = make_uint4(l[0] | (l[1] << 16), l[2] | (l[3] << 16),
                          l[4] | (l[5] << 16), l[6] | (l[7] << 16));
    size_t off = ((size_t)(b * 256 + rb)) * 2048 + kc * 128 + fr * 8;
    short* hi = pk + (size_t)tensor * 2 * PLANE;
    *(uint4*)(hi + off) = hw;
    *(uint4*)(hi + PLANE + off) = lw;
}

// --- 2) E0 = exp((fA.fB^T)*rnA*rnB/temp), pre-packed bf16 hi/lo MFMA ---
__global__ __launch_bounds__(256) void gemm_mfma(
    const short* __restrict__ pk, const float* __restrict__ rn,
    const float* __restrict__ temp, float* __restrict__ E0)
{
    __shared__ short Bs[16384];    // [hi|lo][nb=4][kchunk=16][fr=16][8] = 32 KB
    int b = blockIdx.z;
    int i0 = blockIdx.y * 64, j0 = blockIdx.x * 64;
    int t = threadIdx.x;
    int wave = t >> 6, lane = t & 63;
    int fr = lane & 15;
    int quad = lane >> 4;

    // stage B panel (4 consecutive rowblks = contiguous 16 KB per plane)
    const short* gBhi = pk + 2 * (size_t)PLANE + ((size_t)(b * 256 + (j0 >> 4))) * 2048;
    const short* gBlo = gBhi + PLANE;
    #pragma unroll
    for (int c = 0; c < 4; c++) {
        int ch = c * 256 + t;                       // 0..1023 16B-chunks
        *(uint4*)&Bs[ch * 8]        = *(const uint4*)(gBhi + ch * 8);
        *(uint4*)&Bs[8192 + ch * 8] = *(const uint4*)(gBlo + ch * 8);
    }

    // A fragments for this wave's 16 rows: 8 coalesced 16B loads per lane
    const short* Abase_hi = pk + ((size_t)(b * 256 + (i0 >> 4) + wave)) * 2048;
    const short* Abase_lo = Abase_hi + PLANE;
    bf16x8 ah[4], al[4];
    #pragma unroll
    for (int s = 0; s < 4; s++) {
        ah[s] = *(const bf16x8*)(Abase_hi + s * 512 + lane * 8);
        al[s] = *(const bf16x8*)(Abase_lo + s * 512 + lane * 8);
    }
    __syncthreads();

    f32x4 acc[4] = {f32x4{0,0,0,0}, f32x4{0,0,0,0}, f32x4{0,0,0,0}, f32x4{0,0,0,0}};
    #pragma unroll
    for (int s = 0; s < 4; s++) {                   // k-step = 32 (kchunks s*4..s*4+3)
        int lo = s * 512 + lane * 8;
        #pragma unroll
        for (int nb = 0; nb < 4; nb++) {
            bf16x8 bh = *(const bf16x8*)&Bs[nb * 2048 + lo];
            bf16x8 bl = *(const bf16x8*)&Bs[8192 + nb * 2048 + lo];
            acc[nb] = __builtin_amdgcn_mfma_f32_16x16x32_bf16(ah[s], bh, acc[nb], 0, 0, 0);
            acc[nb] = __builtin_amdgcn_mfma_f32_16x16x32_bf16(al[s], bh, acc[nb], 0, 0, 0);
            acc[nb] = __builtin_amdgcn_mfma_f32_16x16x32_bf16(ah[s], bl, acc[nb], 0, 0, 0);
        }
    }

    float invt = 1.f / temp[0];
    int m0 = i0 + wave * 16 + quad * 4;
    float ra[4];
    #pragma unroll
    for (int rr = 0; rr < 4; rr++) ra[rr] = rn[b * 4096 + m0 + rr] * invt;
    #pragma unroll
    for (int nb = 0; nb < 4; nb++) {
        int col = j0 + nb * 16 + fr;
        float rbv = rn[8192 + b * 4096 + col];
        #pragma unroll
        for (int rr = 0; rr < 4; rr++)
            E0[((size_t)(b * 4096 + m0 + rr)) * 4096 + col] = __expf(acc[nb][rr] * (ra[rr] * rbv));
    }
}

// --- 3) fused Sinkhorn: 4 waves/block, 4 rows/wave, reg-streamed; LDS combine ---
// grid (256,1,2) = 512 blocks = 2/CU (all CUs), 8 waves/CU. Per wave: 4 rows,
// 16 in-flight dwordx4 each; rs -> butterfly -> z_i; cacc += x*z_i (registers).
// End: one 64KB-LDS pass combines the 4 waves' cacc -> ONE slice per block
// (256 slices/batch, fixed order 0+1+2+3 -> deterministic).
__global__ __launch_bounds__(256) void sink_fused(
    const float* __restrict__ E0, float* __restrict__ zu, const float* __restrict__ wv,
    const float* __restrict__ dbp, float* __restrict__ parts)
{
    int b = blockIdx.z;
    int t = threadIdx.x;
    int wave = t >> 6, lane = t & 63;
    int chb = blockIdx.x;                          // 0..255, 16 rows/block
    const float* wb = wv + b * UVS;
    float edb = __expf(dbp[0]);
    __shared__ float S[4][4096];                   // 64 KB combine buffer

    // block 0 / wave 0 refreshes dustbin-row dual: zuN = 0.5/(e^db*sum_j w_j + w_N)
    if (chb == 0 && wave == 0) {
        float sv = 0.f;
        #pragma unroll
        for (int c = 0; c < 16; c++) {
            f32x4 w4 = *(const f32x4*)(wb + lane * 4 + c * 256);
            sv += (w4.x + w4.y) + (w4.z + w4.w);
        }
        #pragma unroll
        for (int off = 32; off > 0; off >>= 1) sv += __shfl_xor(sv, off, 64);
        if (lane == 0) zu[b * UVS + 4096] = HALFC / (edb * sv + wb[4096]);
    }

    float dtail = edb * wb[4096];
    f32x4 cacc[16];
    #pragma unroll
    for (int c = 0; c < 16; c++) cacc[c] = f32x4{0, 0, 0, 0};

    const float* Eb = E0 + ((size_t)b << 24);
    int base = lane * 4;

    for (int r = 0; r < 4; r++) {
        int row = chb * 16 + wave * 4 + r;
        const float* Erow = Eb + ((size_t)row << 12);
        f32x4 x4[16];
        #pragma unroll
        for (int c = 0; c < 16; c++) x4[c] = *(const f32x4*)(Erow + base + c * 256);
        f32x4 rs4 = f32x4{0, 0, 0, 0};
        #pragma unroll
        for (int c = 0; c < 16; c++) {
            f32x4 w4 = *(const f32x4*)(wb + base + c * 256);   // L1-resident (16 KB)
            rs4 += x4[c] * w4;
        }
        float rs = (rs4.x + rs4.y) + (rs4.z + rs4.w);
        #pragma unroll
        for (int off = 32; off > 0; off >>= 1) rs += __shfl_xor(rs, off, 64);
        float zi = EXPC / (rs + dtail);             // identical on all lanes
        if (lane == 0) zu[b * UVS + row] = zi;
        #pragma unroll
        for (int c = 0; c < 16; c++) cacc[c] += x4[c] * zi;
    }

    // combine 4 waves -> 1 slice (deterministic order)
    #pragma unroll
    for (int c = 0; c < 16; c++) *(f32x4*)&S[wave][base + c * 256] = cacc[c];
    __syncthreads();
    float* pp = parts + ((size_t)(b * 256 + chb)) * 4096;
    #pragma unroll
    for (int k = 0; k < 16; k++) {
        int col = t + k * 256;
        pp[col] = (S[0][col] + S[1][col]) + (S[2][col] + S[3][col]);
    }
}

// --- 3b) combine column partials -> w_new[j]; last block handles dustbin ---
// grid (65,1,2): blocks 0..63 each own 64 columns; 4 wave-groups x 64 chunks,
// LDS-combined in fixed order (deterministic). parts = unscaled colsum.
__global__ __launch_bounds__(256) void sink_vB(
    const float* __restrict__ parts, const float* __restrict__ zu,
    float* __restrict__ wv, const float* __restrict__ dbp)
{
    int b = blockIdx.z;
    int t = threadIdx.x;
    float edb = __expf(dbp[0]);
    if (blockIdx.x < 64) {
        int col = blockIdx.x * 64 + (t & 63);
        int grp = t >> 6;                          // 0..3
        float s = 0.f;
        #pragma unroll 8
        for (int ch = grp * 64; ch < grp * 64 + 64; ch++)
            s += parts[((size_t)(b * 256 + ch)) * 4096 + col];
        __shared__ float red[4][64];
        red[grp][t & 63] = s;
        __syncthreads();
        if (grp == 0) {
            float tot = (red[0][t] + red[1][t]) + (red[2][t] + red[3][t]);
            tot += edb * zu[b * UVS + 4096];       // + dustbin row
            wv[b * UVS + col] = EXPC / tot;        // w = e^{v_new}
        }
    } else {
        __shared__ float red2[256];
        float s = 0.f;
        for (int i = t; i < 4096; i += 256) s += zu[b * UVS + i];
        red2[t] = s; __syncthreads();
        for (int off = 128; off > 0; off >>= 1) {
            if (t < off) red2[t] += red2[t + off];
            __syncthreads();
        }
        if (t == 0)
            wv[b * UVS + 4096] = HALFC / (edb * red2[0] + zu[b * UVS + 4096]);
    }
}

// --- 4) per-row top-8 of E0*w: wave-per-row, med3 network + threshold + rank ---
#define FCMPSWAP(a, b) { float _mx = fmaxf(a, b), _mn = fminf(a, b); (a) = _mx; (b) = _mn; }
__global__ __launch_bounds__(256) void topk_kernel(
    const float* __restrict__ E0, const float* __restrict__ zu, const float* __restrict__ wv,
    const float* __restrict__ posA, const float* __restrict__ posB,
    float* __restrict__ tkv, float* __restrict__ tkp, float* __restrict__ dp)
{
    int wave = threadIdx.x >> 6;
    int lane = threadIdx.x & 63;
    int row = blockIdx.x * 4 + wave;                 // 0..8191 == b*4096+i
    int b = row >> 12; int i = row & 4095;
    const float* Erow = E0 + (size_t)row * 4096;
    const float* wb = wv + b * UVS;

    __shared__ unsigned long long cand[4][64];
    __shared__ int ccnt[4];
    if (lane == 0) ccnt[wave] = 0;

    // pass 1: cache q in registers, branchless per-lane sorted top-8 (med3)
    f32x4 q[16];
    float s[8] = {0, 0, 0, 0, 0, 0, 0, 0};
    #pragma unroll
    for (int c = 0; c < 16; c++) {
        int j = c * 256 + lane * 4;
        f32x4 x = *(const f32x4*)(Erow + j);
        f32x4 w = *(const f32x4*)(wb + j);
        q[c] = x * w;
        float el[4] = {q[c].x, q[c].y, q[c].z, q[c].w};
        #pragma unroll
        for (int e = 0; e < 4; e++) {
            float xv = el[e];
            s[7] = __builtin_amdgcn_fmed3f(s[6], s[7], xv);
            s[6] = __builtin_amdgcn_fmed3f(s[5], s[6], xv);
            s[5] = __builtin_amdgcn_fmed3f(s[4], s[5], xv);
            s[4] = __builtin_amdgcn_fmed3f(s[3], s[4], xv);
            s[3] = __builtin_amdgcn_fmed3f(s[2], s[3], xv);
            s[2] = __builtin_amdgcn_fmed3f(s[1], s[2], xv);
            s[1] = __builtin_amdgcn_fmed3f(s[0], s[1], xv);
            s[0] = fmaxf(s[0], xv);
        }
    }

    // f32 butterfly merge: all lanes end with the row's sorted top-8 values
    #pragma unroll
    for (int st = 0; st < 6; st++) {
        int off = 1 << st;
        float o[8];
        #pragma unroll
        for (int r = 0; r < 8; r++) o[r] = __shfl_xor(s[r], off, 64);
        float m[8];
        #pragma unroll
        for (int r = 0; r < 8; r++) m[r] = fmaxf(s[r], o[7 - r]);   // bitonic union top-8
        FCMPSWAP(m[0], m[4]); FCMPSWAP(m[1], m[5]); FCMPSWAP(m[2], m[6]); FCMPSWAP(m[3], m[7]);
        FCMPSWAP(m[0], m[2]); FCMPSWAP(m[1], m[3]); FCMPSWAP(m[4], m[6]); FCMPSWAP(m[5], m[7]);
        FCMPSWAP(m[0], m[1]); FCMPSWAP(m[2], m[3]); FCMPSWAP(m[4], m[5]); FCMPSWAP(m[6], m[7]);
        #pragma unroll
        for (int r = 0; r < 8; r++) s[r] = m[r];
    }
    float t8 = s[7];                                 // true 8th-largest value

    __syncthreads();                                 // ccnt init visible

    // pass 2: register rescan vs threshold; push exact keys (rare: ~8/row)
    #pragma unroll
    for (int c = 0; c < 16; c++) {
        float el[4] = {q[c].x, q[c].y, q[c].z, q[c].w};
        #pragma unroll
        for (int e = 0; e < 4; e++) {
            if (el[e] >= t8) {
                int j = c * 256 + lane * 4 + e;
                unsigned long long key =
                    ((unsigned long long)__float_as_uint(el[e]) << 32) | (unsigned)(4095 - j);
                int slot = atomicAdd(&ccnt[wave], 1);
                if (slot < 64) cand[wave][slot] = key;
            }
        }
    }
    __syncthreads();

    // rank select over the pool (cnt >= 8 guaranteed; keys distinct via index)
    int cnt = ccnt[wave]; if (cnt > 64) cnt = 64;
    if (lane < cnt) {
        unsigned long long my = cand[wave][lane];
        int rank = 0;
        for (int j2 = 0; j2 < cnt; j2++) rank += (cand[wave][j2] > my) ? 1 : 0;
        if (rank < 8) {
            int idx = 4095 - (int)(my & 0xFFFFFFFFu);
            float candv = __uint_as_float((unsigned)(my >> 32));
            float val = candv * zu[b * UVS + i];     // p = E0*w*z
            float px = posB[((size_t)(b * 4096 + idx)) * 2 + 0];
            float py = posB[((size_t)(b * 4096 + idx)) * 2 + 1];
            float ax = posA[((size_t)(b * 4096 + i)) * 2 + 0];
            float ay = posA[((size_t)(b * 4096 + i)) * 2 + 1];
            size_t base = ((size_t)(b * 4096 + i)) * 8 + rank;
            tkv[base] = val;
            tkp[base * 2 + 0] = px; tkp[base * 2 + 1] = py;
            dp[((size_t)((b * 8 + rank) * 2 + 0)) * 4096 + i] = px - ax;
            dp[((size_t)((b * 8 + rank) * 2 + 1)) * 4096 + i] = py - ay;
        }
    }
}

// --- 5) geo: 7x7 windowed variance (count_include_pad=False) ---
__global__ __launch_bounds__(256) void geo_kernel(
    const float* __restrict__ dp, float* __restrict__ geo)
{
    int tid = blockIdx.x * 256 + threadIdx.x;   // 65536
    int n = tid & 4095; int bk = tid >> 12;
    int b = bk >> 3; int k = bk & 7;
    int h = n >> 6, w = n & 63;
    const float* dpx = dp + ((size_t)(bk * 2 + 0)) * 4096;
    const float* dpy = dp + ((size_t)(bk * 2 + 1)) * 4096;
    float sx = 0, sy = 0, sxx = 0, syy = 0, cnt = 0;
    #pragma unroll
    for (int dy = -3; dy <= 3; dy++) {
        int hh = h + dy; if ((unsigned)hh >= 64u) continue;
        #pragma unroll
        for (int dx = -3; dx <= 3; dx++) {
            int ww = w + dx; if ((unsigned)ww >= 64u) continue;
            int nn = (hh << 6) + ww;
            float vx = dpx[nn], vy = dpy[nn];
            sx += vx; sy += vy; sxx += vx * vx; syy += vy * vy; cnt += 1.f;
        }
    }
    float inv = 1.f / cnt;
    float mx = sx * inv, my = sy * inv;
    float varx = fmaxf(sxx * inv - mx * mx, 0.f);
    float vary = fmaxf(syy * inv - my * my, 0.f);
    geo[((size_t)(b * 4096 + n)) * 8 + k] = 1.f / (1.f + 100.f * (varx + vary));
}

// --- 6) softmax refine -> refined_warp + conf ---
__global__ __launch_bounds__(256) void refine_kernel(
    const float* __restrict__ tkv, const float* __restrict__ geo,
    const float* __restrict__ tkp, const float* __restrict__ gwp,
    const float* __restrict__ tpp, float* __restrict__ out)
{
    int tid = blockIdx.x * 256 + threadIdx.x;   // 0..8191
    float gw = fminf(fmaxf(gwp[0], 0.f), 2.f);
    float invt = 1.f / tpp[0];
    size_t base = (size_t)tid * 8;
    float cb[8], vv[8];
    float mx = -INFINITY;
    #pragma unroll
    for (int k = 0; k < 8; k++) { vv[k] = tkv[base + k]; cb[k] = vv[k] + gw * geo[base + k]; mx = fmaxf(mx, cb[k]); }
    float e[8], se = 0;
    #pragma unroll
    for (int k = 0; k < 8; k++) { e[k] = __expf((cb[k] - mx) * invt); se += e[k]; }
    float wx = 0, wy = 0, cf = 0; float inv = 1.f / se;
    #pragma unroll
    for (int k = 0; k < 8; k++) {
        float s = e[k] * inv;
        wx += s * tkp[(base + k) * 2 + 0];
        wy += s * tkp[(base + k) * 2 + 1];
        cf += s * vv[k];
    }
    out[(size_t)tid * 2 + 0] = wx;
    out[(size_t)tid * 2 + 1] = wy;
    out[16384 + tid] = cf;
}

// --- 7) weighted affine: 12 sums per batch (double) ---
__global__ __launch_bounds__(256) void affine_reduce(
    const float* __restrict__ posA, const float* __restrict__ out, double* __restrict__ sums)
{
    int b = blockIdx.x; int t = threadIdx.x;
    double acc[12] = {0,0,0,0,0,0,0,0,0,0,0,0};
    for (int n = t; n < 4096; n += 256) {
        size_t idx = (size_t)b * 4096 + n;
        float x = posA[idx * 2], y = posA[idx * 2 + 1];
        float dx = out[idx * 2], dy = out[idx * 2 + 1];
        float c = out[16384 + idx];
        double cd = (double)c;
        double cx = cd * x, cy = cd * y;
        acc[0] += cx * x;  acc[1] += cx * y;  acc[2] += cy * y;
        acc[3] += cx;      acc[4] += cy;      acc[5] += cd;
        acc[6] += cx * dx; acc[7] += cy * dx; acc[8] += cd * dx;
        acc[9] += cx * dy; acc[10] += cy * dy; acc[11] += cd * dy;
    }
    __shared__ double red[256];
    for (int s = 0; s < 12; s++) {
        red[t] = acc[s]; __syncthreads();
        for (int off = 128; off > 0; off >>= 1) {
            if (t < off) red[t] += red[t + off];
            __syncthreads();
        }
        if (t == 0) sums[b * 12 + s] = red[0];
        __syncthreads();
    }
}

// --- 8) closed-form 3x3 solve (AtWA block-diagonal) ---
__global__ void affine_solve(const double* __restrict__ sums, float* __restrict__ out)
{
    int t = threadIdx.x;
    if (t >= 2) return;
    int b = t;
    const double* s = sums + b * 12;
    double den = s[5] > 1e-6 ? s[5] : 1e-6;
    double g00 = s[0] / den + 1e-4, g01 = s[1] / den, g02 = s[3] / den;
    double g11 = s[2] / den + 1e-4, g12 = s[4] / den;
    double g22 = s[5] / den + 1e-4;
    double bx0 = s[6] / den, bx1 = s[7] / den, bx2 = s[8] / den;
    double by0 = s[9] / den, by1 = s[10] / den, by2 = s[11] / den;
    double c00 = g11 * g22 - g12 * g12;
    double c01 = g02 * g12 - g01 * g22;
    double c02 = g01 * g12 - g02 * g11;
    double det = g00 * c00 + g01 * c01 + g02 * c02;
    double id = 1.0 / det;
    double i00 = c00 * id, i01 = c01 * id, i02 = c02 * id;
    double i11 = (g00 * g22 - g02 * g02) * id, i12 = (g01 * g02 - g00 * g12) * id;
    double i22 = (g00 * g11 - g01 * g01) * id;
    double a_ = i00 * bx0 + i01 * bx1 + i02 * bx2;
    double b_ = i01 * bx0 + i11 * bx1 + i12 * bx2;
    double c_ = i02 * bx0 + i12 * bx1 + i22 * bx2;
    double d_ = i00 * by0 + i01 * by1 + i02 * by2;
    double e_ = i01 * by0 + i11 * by1 + i12 * by2;
    double f_ = i02 * by0 + i12 * by1 + i22 * by2;
    float* o = out + 24576 + b * 9;
    o[0] = (float)a_; o[1] = (float)b_; o[2] = (float)c_;
    o[3] = (float)d_; o[4] = (float)e_; o[5] = (float)f_;
    o[6] = 0.f; o[7] = 0.f; o[8] = 1.f;
}

extern "C" void kernel_launch(void* const* d_in, const int* in_sizes, int n_in,
                              void* d_out, int out_size, void* d_ws, size_t ws_size,
                              hipStream_t stream) {
    const float* fA = (const float*)d_in[0];
    const float* fB = (const float*)d_in[1];
    const float* pA = (const float*)d_in[2];
    const float* pB = (const float*)d_in[3];
    const float* db = (const float*)d_in[4];
    const float* gw = (const float*)d_in[5];
    const float* tp = (const float*)d_in[6];

    float* ws    = (float*)d_ws;
    float* out   = (float*)d_out;
    float* E0    = ws;
    float* zu    = ws + OFF_ZU;
    float* wv    = ws + OFF_WV;
    float* rn    = ws + OFF_RN;
    float* parts = ws + OFF_PARTS;
    short* pk    = (short*)(ws + OFF_PARTS);   // pack planes live in parts (time-shared)
    float* tkv   = ws + OFF_TKV;
    float* tkp   = ws + OFF_TKP;
    float* dp    = ws + OFF_DP;
    float* geo   = ws + OFF_GEO;
    double* sums = (double*)(ws + OFF_SUM);

    init_kernel<<<33, 256, 0, stream>>>(wv);                 // w = e^0 = 1
    norms_kernel<<<4096, 256, 0, stream>>>(fA, fB, rn);
    pack_kernel<<<1024, 256, 0, stream>>>(fA, fB, pk);
    gemm_mfma<<<dim3(64, 64, 2), 256, 0, stream>>>(pk, rn, tp, E0);

    for (int it = 0; it < 5; it++) {
        sink_fused<<<dim3(256, 1, 2), 256, 0, stream>>>(E0, zu, wv, db, parts);
        sink_vB<<<dim3(65, 1, 2), 256, 0, stream>>>(parts, zu, wv, db);
    }

    topk_kernel<<<2048, 256, 0, stream>>>(E0, zu, wv, pA, pB, tkv, tkp, dp);
    geo_kernel<<<256, 256, 0, stream>>>(dp, geo);
    refine_kernel<<<32, 256, 0, stream>>>(tkv, geo, tkp, gw, tp, out);
    affine_reduce<<<2, 256, 0, stream>>>(pA, out, sums);
    affine_solve<<<1, 64, 0, stream>>>(sums, out);
}

// Round 8
// 321.215 us; speedup vs baseline: 1.2308x; 1.0064x over previous
//
#include <hip/hip_runtime.h>
#include <math.h>

// B=2, H=W=64, N=4096, C=128, K=8, 5 Sinkhorn iters.
// Workspace holds E0 = exp(S) (fp32, selection-safe); duals kept as w=e^v, z=e^u.
#define UVS 4104   // padded dual-array batch stride (float4-aligned)

// Workspace layout (float offsets)
#define OFF_ZU    33554432ul               // 2*4096*4096 floats of E0 first
#define OFF_WV    (OFF_ZU + 2*UVS)
#define OFF_RN    (OFF_WV + 2*UVS)         // 16384 (rnA | rnB)
#define OFF_PARTS (OFF_RN + 16384)         // 2*256*4096 col partials / bf16 pack (time-shared)
#define OFF_TKV   (OFF_PARTS + 2097152)    // 2*4096*8
#define OFF_TKP   (OFF_TKV + 65536)        // 2*4096*8*2
#define OFF_DP    (OFF_TKP + 131072)       // 2*8*2*4096 planar
#define OFF_GEO   (OFF_DP + 131072)        // 2*4096*8
#define OFF_SUM   (OFF_GEO + 65536)        // 24 doubles

#define EXPC    0.0001220703125f           // e^NORMC = 1/8192
#define HALFC   0.5f                       // e^{log(N)+NORMC} = 1/2

#define PLANE   1048576                    // shorts per pack plane: 2*256*16*16*8

typedef __attribute__((ext_vector_type(8))) short bf16x8;
typedef __attribute__((ext_vector_type(4))) float f32x4;

static __device__ __forceinline__ unsigned f2bf(float x) {  // RTNE fp32->bf16 bits
    unsigned u = __float_as_uint(x);
    return (u + 0x7FFFu + ((u >> 16) & 1u)) >> 16;
}
static __device__ __forceinline__ float bf2f(unsigned h) { return __uint_as_float(h << 16); }

// --- 0) init duals: w = e^0 = 1 everywhere (incl. dustbin) ---
__global__ __launch_bounds__(256) void init_kernel(float* __restrict__ wv)
{
    int i = blockIdx.x * 256 + threadIdx.x;
    if (i < 2 * UVS) wv[i] = 1.0f;
}

// --- 1) inverse L2 norms ---
__global__ __launch_bounds__(256) void norms_kernel(
    const float* __restrict__ fA, const float* __restrict__ fB, float* __restrict__ rn)
{
    int t = threadIdx.x;
    int rowg = blockIdx.x * 4 + (t >> 6);
    int lane = t & 63;
    const float* f = (rowg < 8192) ? fA : fB;
    int r = rowg & 8191;
    float x0 = f[(size_t)r * 128 + lane];
    float x1 = f[(size_t)r * 128 + 64 + lane];
    float s = x0 * x0 + x1 * x1;
    #pragma unroll
    for (int off = 32; off > 0; off >>= 1) s += __shfl_xor(s, off, 64);
    if (lane == 0) rn[rowg] = 1.f / fmaxf(sqrtf(s), 1e-12f);
}

// --- 1b) one-time fp32 -> hi/lo bf16 conversion, fragment-major layout ---
__global__ __launch_bounds__(256) void pack_kernel(
    const float* __restrict__ fA, const float* __restrict__ fB, short* __restrict__ pk)
{
    int gt = blockIdx.x * 256 + threadIdx.x;   // 0..262143
    int tensor = gt >> 17;                      // 0 = A, 1 = B
    int t = gt & 131071;                        // (b, rb, kc, fr)
    int fr = t & 15;
    int kc = (t >> 4) & 15;
    int rb = (t >> 8) & 255;
    int b  = t >> 16;
    const float* src = tensor ? fB : fA;
    const float* p = src + ((size_t)(b * 4096 + rb * 16 + fr)) * 128 + kc * 8;
    float4 v0 = *(const float4*)p;
    float4 v1 = *(const float4*)(p + 4);
    float el[8] = {v0.x, v0.y, v0.z, v0.w, v1.x, v1.y, v1.z, v1.w};
    unsigned h[8], l[8];
    #pragma unroll
    for (int e = 0; e < 8; e++) { h[e] = f2bf(el[e]); l[e] = f2bf(el[e] - bf2f(h[e])); }
    uint4 hw = make_uint4(h[0] | (h[1] << 16), h[2] | (h[3] << 16),
                          h[4] | (h[5] << 16), h[6] | (h[7] << 16));
    uint4 lw = make_uint4(l[0] | (l[1] << 16), l[2] | (l[3] << 16),
                          l[4] | (l[5] << 16), l[6] | (l[7] << 16));
    size_t off = ((size_t)(b * 256 + rb)) * 2048 + kc * 128 + fr * 8;
    short* hi = pk + (size_t)tensor * 2 * PLANE;
    *(uint4*)(hi + off) = hw;
    *(uint4*)(hi + PLANE + off) = lw;
}

// --- 2) E0 = exp((fA.fB^T)*rnA*rnB/temp), pre-packed bf16 hi/lo MFMA ---
__global__ __launch_bounds__(256) void gemm_mfma(
    const short* __restrict__ pk, const float* __restrict__ rn,
    const float* __restrict__ temp, float* __restrict__ E0)
{
    __shared__ short Bs[16384];    // [hi|lo][nb=4][kchunk=16][fr=16][8] = 32 KB
    int b = blockIdx.z;
    int i0 = blockIdx.y * 64, j0 = blockIdx.x * 64;
    int t = threadIdx.x;
    int wave = t >> 6, lane = t & 63;
    int fr = lane & 15;
    int quad = lane >> 4;

    // stage B panel (4 consecutive rowblks = contiguous 16 KB per plane)
    const short* gBhi = pk + 2 * (size_t)PLANE + ((size_t)(b * 256 + (j0 >> 4))) * 2048;
    const short* gBlo = gBhi + PLANE;
    #pragma unroll
    for (int c = 0; c < 4; c++) {
        int ch = c * 256 + t;                       // 0..1023 16B-chunks
        *(uint4*)&Bs[ch * 8]        = *(const uint4*)(gBhi + ch * 8);
        *(uint4*)&Bs[8192 + ch * 8] = *(const uint4*)(gBlo + ch * 8);
    }

    // A fragments for this wave's 16 rows: 8 coalesced 16B loads per lane
    const short* Abase_hi = pk + ((size_t)(b * 256 + (i0 >> 4) + wave)) * 2048;
    const short* Abase_lo = Abase_hi + PLANE;
    bf16x8 ah[4], al[4];
    #pragma unroll
    for (int s = 0; s < 4; s++) {
        ah[s] = *(const bf16x8*)(Abase_hi + s * 512 + lane * 8);
        al[s] = *(const bf16x8*)(Abase_lo + s * 512 + lane * 8);
    }
    __syncthreads();

    f32x4 acc[4] = {f32x4{0,0,0,0}, f32x4{0,0,0,0}, f32x4{0,0,0,0}, f32x4{0,0,0,0}};
    #pragma unroll
    for (int s = 0; s < 4; s++) {                   // k-step = 32 (kchunks s*4..s*4+3)
        int lo = s * 512 + lane * 8;
        #pragma unroll
        for (int nb = 0; nb < 4; nb++) {
            bf16x8 bh = *(const bf16x8*)&Bs[nb * 2048 + lo];
            bf16x8 bl = *(const bf16x8*)&Bs[8192 + nb * 2048 + lo];
            acc[nb] = __builtin_amdgcn_mfma_f32_16x16x32_bf16(ah[s], bh, acc[nb], 0, 0, 0);
            acc[nb] = __builtin_amdgcn_mfma_f32_16x16x32_bf16(al[s], bh, acc[nb], 0, 0, 0);
            acc[nb] = __builtin_amdgcn_mfma_f32_16x16x32_bf16(ah[s], bl, acc[nb], 0, 0, 0);
        }
    }

    float invt = 1.f / temp[0];
    int m0 = i0 + wave * 16 + quad * 4;
    float ra[4];
    #pragma unroll
    for (int rr = 0; rr < 4; rr++) ra[rr] = rn[b * 4096 + m0 + rr] * invt;
    #pragma unroll
    for (int nb = 0; nb < 4; nb++) {
        int col = j0 + nb * 16 + fr;
        float rbv = rn[8192 + b * 4096 + col];
        #pragma unroll
        for (int rr = 0; rr < 4; rr++)
            E0[((size_t)(b * 4096 + m0 + rr)) * 4096 + col] = __expf(acc[nb][rr] * (ra[rr] * rbv));
    }
}

// --- 3) fused Sinkhorn: 4 waves/block, 4 rows/wave, reg-streamed; LDS combine ---
__global__ __launch_bounds__(256) void sink_fused(
    const float* __restrict__ E0, float* __restrict__ zu, const float* __restrict__ wv,
    const float* __restrict__ dbp, float* __restrict__ parts)
{
    int b = blockIdx.z;
    int t = threadIdx.x;
    int wave = t >> 6, lane = t & 63;
    int chb = blockIdx.x;                          // 0..255, 16 rows/block
    const float* wb = wv + b * UVS;
    float edb = __expf(dbp[0]);
    __shared__ float S[4][4096];                   // 64 KB combine buffer

    // block 0 / wave 0 refreshes dustbin-row dual: zuN = 0.5/(e^db*sum_j w_j + w_N)
    if (chb == 0 && wave == 0) {
        float sv = 0.f;
        #pragma unroll
        for (int c = 0; c < 16; c++) {
            f32x4 w4 = *(const f32x4*)(wb + lane * 4 + c * 256);
            sv += (w4.x + w4.y) + (w4.z + w4.w);
        }
        #pragma unroll
        for (int off = 32; off > 0; off >>= 1) sv += __shfl_xor(sv, off, 64);
        if (lane == 0) zu[b * UVS + 4096] = HALFC / (edb * sv + wb[4096]);
    }

    float dtail = edb * wb[4096];
    f32x4 cacc[16];
    #pragma unroll
    for (int c = 0; c < 16; c++) cacc[c] = f32x4{0, 0, 0, 0};

    const float* Eb = E0 + ((size_t)b << 24);
    int base = lane * 4;

    for (int r = 0; r < 4; r++) {
        int row = chb * 16 + wave * 4 + r;
        const float* Erow = Eb + ((size_t)row << 12);
        f32x4 x4[16];
        #pragma unroll
        for (int c = 0; c < 16; c++) x4[c] = *(const f32x4*)(Erow + base + c * 256);
        f32x4 rs4 = f32x4{0, 0, 0, 0};
        #pragma unroll
        for (int c = 0; c < 16; c++) {
            f32x4 w4 = *(const f32x4*)(wb + base + c * 256);   // L1-resident (16 KB)
            rs4 += x4[c] * w4;
        }
        float rs = (rs4.x + rs4.y) + (rs4.z + rs4.w);
        #pragma unroll
        for (int off = 32; off > 0; off >>= 1) rs += __shfl_xor(rs, off, 64);
        float zi = EXPC / (rs + dtail);             // identical on all lanes
        if (lane == 0) zu[b * UVS + row] = zi;
        #pragma unroll
        for (int c = 0; c < 16; c++) cacc[c] += x4[c] * zi;
    }

    // combine 4 waves -> 1 slice (deterministic order)
    #pragma unroll
    for (int c = 0; c < 16; c++) *(f32x4*)&S[wave][base + c * 256] = cacc[c];
    __syncthreads();
    float* pp = parts + ((size_t)(b * 256 + chb)) * 4096;
    #pragma unroll
    for (int k = 0; k < 16; k++) {
        int col = t + k * 256;
        pp[col] = (S[0][col] + S[1][col]) + (S[2][col] + S[3][col]);
    }
}

// --- 3b) combine column partials -> w_new[j]; last block handles dustbin ---
__global__ __launch_bounds__(256) void sink_vB(
    const float* __restrict__ parts, const float* __restrict__ zu,
    float* __restrict__ wv, const float* __restrict__ dbp)
{
    int b = blockIdx.z;
    int t = threadIdx.x;
    float edb = __expf(dbp[0]);
    if (blockIdx.x < 64) {
        int col = blockIdx.x * 64 + (t & 63);
        int grp = t >> 6;                          // 0..3
        float s = 0.f;
        #pragma unroll 8
        for (int ch = grp * 64; ch < grp * 64 + 64; ch++)
            s += parts[((size_t)(b * 256 + ch)) * 4096 + col];
        __shared__ float red[4][64];
        red[grp][t & 63] = s;
        __syncthreads();
        if (grp == 0) {
            float tot = (red[0][t] + red[1][t]) + (red[2][t] + red[3][t]);
            tot += edb * zu[b * UVS + 4096];       // + dustbin row
            wv[b * UVS + col] = EXPC / tot;        // w = e^{v_new}
        }
    } else {
        __shared__ float red2[256];
        float s = 0.f;
        for (int i = t; i < 4096; i += 256) s += zu[b * UVS + i];
        red2[t] = s; __syncthreads();
        for (int off = 128; off > 0; off >>= 1) {
            if (t < off) red2[t] += red2[t + off];
            __syncthreads();
        }
        if (t == 0)
            wv[b * UVS + 4096] = HALFC / (edb * red2[0] + zu[b * UVS + 4096]);
    }
}

// --- 4) per-row top-8 of E0*w: wave-per-row, LOAD/COMPUTE-SPLIT med3 select ---
// Phase A: issue ALL 32 dwordx4 loads (E0 row + w) and form q[16] — nothing
// else. sched_barrier(0) pins the boundary (stops hipcc re-interleaving; R7's
// VGPR=56 proved the compiler was serializing loads into the insert chain,
// exposing ~700cy latency 16x per row). Phase B: med3 insertion from registers.
// Then f32 butterfly -> exact t8; register rescan pushes exact u64 keys
// (value_bits<<32 | 4095-j) to a pool; rank select = exact lax.top_k.
#define FCMPSWAP(a, b) { float _mx = fmaxf(a, b), _mn = fminf(a, b); (a) = _mx; (b) = _mn; }
__global__ __launch_bounds__(256) void topk_kernel(
    const float* __restrict__ E0, const float* __restrict__ zu, const float* __restrict__ wv,
    const float* __restrict__ posA, const float* __restrict__ posB,
    float* __restrict__ tkv, float* __restrict__ tkp, float* __restrict__ dp)
{
    int wave = threadIdx.x >> 6;
    int lane = threadIdx.x & 63;
    int row = blockIdx.x * 4 + wave;                 // 0..8191 == b*4096+i
    int b = row >> 12; int i = row & 4095;
    const float* Erow = E0 + (size_t)row * 4096;
    const float* wb = wv + b * UVS;

    __shared__ unsigned long long cand[4][64];
    __shared__ int ccnt[4];
    if (lane == 0) ccnt[wave] = 0;

    // phase A: all loads in flight, q[16] formed (64 VGPRs, kept live)
    f32x4 q[16];
    #pragma unroll
    for (int c = 0; c < 16; c++) {
        int j = c * 256 + lane * 4;
        f32x4 x = *(const f32x4*)(Erow + j);
        f32x4 w = *(const f32x4*)(wb + j);
        q[c] = x * w;
    }
    __builtin_amdgcn_sched_barrier(0);               // pin: no insert before loads issued

    // phase B: branchless per-lane sorted top-8 (med3 insertion), registers only
    float s[8] = {0, 0, 0, 0, 0, 0, 0, 0};
    #pragma unroll
    for (int c = 0; c < 16; c++) {
        float el[4] = {q[c].x, q[c].y, q[c].z, q[c].w};
        #pragma unroll
        for (int e = 0; e < 4; e++) {
            float xv = el[e];
            s[7] = __builtin_amdgcn_fmed3f(s[6], s[7], xv);
            s[6] = __builtin_amdgcn_fmed3f(s[5], s[6], xv);
            s[5] = __builtin_amdgcn_fmed3f(s[4], s[5], xv);
            s[4] = __builtin_amdgcn_fmed3f(s[3], s[4], xv);
            s[3] = __builtin_amdgcn_fmed3f(s[2], s[3], xv);
            s[2] = __builtin_amdgcn_fmed3f(s[1], s[2], xv);
            s[1] = __builtin_amdgcn_fmed3f(s[0], s[1], xv);
            s[0] = fmaxf(s[0], xv);
        }
    }

    // f32 butterfly merge: all lanes end with the row's sorted top-8 values
    #pragma unroll
    for (int st = 0; st < 6; st++) {
        int off = 1 << st;
        float o[8];
        #pragma unroll
        for (int r = 0; r < 8; r++) o[r] = __shfl_xor(s[r], off, 64);
        float m[8];
        #pragma unroll
        for (int r = 0; r < 8; r++) m[r] = fmaxf(s[r], o[7 - r]);   // bitonic union top-8
        FCMPSWAP(m[0], m[4]); FCMPSWAP(m[1], m[5]); FCMPSWAP(m[2], m[6]); FCMPSWAP(m[3], m[7]);
        FCMPSWAP(m[0], m[2]); FCMPSWAP(m[1], m[3]); FCMPSWAP(m[4], m[6]); FCMPSWAP(m[5], m[7]);
        FCMPSWAP(m[0], m[1]); FCMPSWAP(m[2], m[3]); FCMPSWAP(m[4], m[5]); FCMPSWAP(m[6], m[7]);
        #pragma unroll
        for (int r = 0; r < 8; r++) s[r] = m[r];
    }
    float t8 = s[7];                                 // true 8th-largest value

    __syncthreads();                                 // ccnt init visible

    // pass 2: register rescan vs threshold; push exact keys (rare: ~8/row)
    #pragma unroll
    for (int c = 0; c < 16; c++) {
        float el[4] = {q[c].x, q[c].y, q[c].z, q[c].w};
        #pragma unroll
        for (int e = 0; e < 4; e++) {
            if (el[e] >= t8) {
                int j = c * 256 + lane * 4 + e;
                unsigned long long key =
                    ((unsigned long long)__float_as_uint(el[e]) << 32) | (unsigned)(4095 - j);
                int slot = atomicAdd(&ccnt[wave], 1);
                if (slot < 64) cand[wave][slot] = key;
            }
        }
    }
    __syncthreads();

    // rank select over the pool (cnt >= 8 guaranteed; keys distinct via index)
    int cnt = ccnt[wave]; if (cnt > 64) cnt = 64;
    if (lane < cnt) {
        unsigned long long my = cand[wave][lane];
        int rank = 0;
        for (int j2 = 0; j2 < cnt; j2++) rank += (cand[wave][j2] > my) ? 1 : 0;
        if (rank < 8) {
            int idx = 4095 - (int)(my & 0xFFFFFFFFu);
            float candv = __uint_as_float((unsigned)(my >> 32));
            float val = candv * zu[b * UVS + i];     // p = E0*w*z
            float px = posB[((size_t)(b * 4096 + idx)) * 2 + 0];
            float py = posB[((size_t)(b * 4096 + idx)) * 2 + 1];
            float ax = posA[((size_t)(b * 4096 + i)) * 2 + 0];
            float ay = posA[((size_t)(b * 4096 + i)) * 2 + 1];
            size_t base = ((size_t)(b * 4096 + i)) * 8 + rank;
            tkv[base] = val;
            tkp[base * 2 + 0] = px; tkp[base * 2 + 1] = py;
            dp[((size_t)((b * 8 + rank) * 2 + 0)) * 4096 + i] = px - ax;
            dp[((size_t)((b * 8 + rank) * 2 + 1)) * 4096 + i] = py - ay;
        }
    }
}

// --- 5) geo: 7x7 windowed variance (count_include_pad=False) ---
__global__ __launch_bounds__(256) void geo_kernel(
    const float* __restrict__ dp, float* __restrict__ geo)
{
    int tid = blockIdx.x * 256 + threadIdx.x;   // 65536
    int n = tid & 4095; int bk = tid >> 12;
    int b = bk >> 3; int k = bk & 7;
    int h = n >> 6, w = n & 63;
    const float* dpx = dp + ((size_t)(bk * 2 + 0)) * 4096;
    const float* dpy = dp + ((size_t)(bk * 2 + 1)) * 4096;
    float sx = 0, sy = 0, sxx = 0, syy = 0, cnt = 0;
    #pragma unroll
    for (int dy = -3; dy <= 3; dy++) {
        int hh = h + dy; if ((unsigned)hh >= 64u) continue;
        #pragma unroll
        for (int dx = -3; dx <= 3; dx++) {
            int ww = w + dx; if ((unsigned)ww >= 64u) continue;
            int nn = (hh << 6) + ww;
            float vx = dpx[nn], vy = dpy[nn];
            sx += vx; sy += vy; sxx += vx * vx; syy += vy * vy; cnt += 1.f;
        }
    }
    float inv = 1.f / cnt;
    float mx = sx * inv, my = sy * inv;
    float varx = fmaxf(sxx * inv - mx * mx, 0.f);
    float vary = fmaxf(syy * inv - my * my, 0.f);
    geo[((size_t)(b * 4096 + n)) * 8 + k] = 1.f / (1.f + 100.f * (varx + vary));
}

// --- 6) softmax refine -> refined_warp + conf ---
__global__ __launch_bounds__(256) void refine_kernel(
    const float* __restrict__ tkv, const float* __restrict__ geo,
    const float* __restrict__ tkp, const float* __restrict__ gwp,
    const float* __restrict__ tpp, float* __restrict__ out)
{
    int tid = blockIdx.x * 256 + threadIdx.x;   // 0..8191
    float gw = fminf(fmaxf(gwp[0], 0.f), 2.f);
    float invt = 1.f / tpp[0];
    size_t base = (size_t)tid * 8;
    float cb[8], vv[8];
    float mx = -INFINITY;
    #pragma unroll
    for (int k = 0; k < 8; k++) { vv[k] = tkv[base + k]; cb[k] = vv[k] + gw * geo[base + k]; mx = fmaxf(mx, cb[k]); }
    float e[8], se = 0;
    #pragma unroll
    for (int k = 0; k < 8; k++) { e[k] = __expf((cb[k] - mx) * invt); se += e[k]; }
    float wx = 0, wy = 0, cf = 0; float inv = 1.f / se;
    #pragma unroll
    for (int k = 0; k < 8; k++) {
        float s = e[k] * inv;
        wx += s * tkp[(base + k) * 2 + 0];
        wy += s * tkp[(base + k) * 2 + 1];
        cf += s * vv[k];
    }
    out[(size_t)tid * 2 + 0] = wx;
    out[(size_t)tid * 2 + 1] = wy;
    out[16384 + tid] = cf;
}

// --- 7) weighted affine: 12 sums per batch (double) ---
__global__ __launch_bounds__(256) void affine_reduce(
    const float* __restrict__ posA, const float* __restrict__ out, double* __restrict__ sums)
{
    int b = blockIdx.x; int t = threadIdx.x;
    double acc[12] = {0,0,0,0,0,0,0,0,0,0,0,0};
    for (int n = t; n < 4096; n += 256) {
        size_t idx = (size_t)b * 4096 + n;
        float x = posA[idx * 2], y = posA[idx * 2 + 1];
        float dx = out[idx * 2], dy = out[idx * 2 + 1];
        float c = out[16384 + idx];
        double cd = (double)c;
        double cx = cd * x, cy = cd * y;
        acc[0] += cx * x;  acc[1] += cx * y;  acc[2] += cy * y;
        acc[3] += cx;      acc[4] += cy;      acc[5] += cd;
        acc[6] += cx * dx; acc[7] += cy * dx; acc[8] += cd * dx;
        acc[9] += cx * dy; acc[10] += cy * dy; acc[11] += cd * dy;
    }
    __shared__ double red[256];
    for (int s = 0; s < 12; s++) {
        red[t] = acc[s]; __syncthreads();
        for (int off = 128; off > 0; off >>= 1) {
            if (t < off) red[t] += red[t + off];
            __syncthreads();
        }
        if (t == 0) sums[b * 12 + s] = red[0];
        __syncthreads();
    }
}

// --- 8) closed-form 3x3 solve (AtWA block-diagonal) ---
__global__ void affine_solve(const double* __restrict__ sums, float* __restrict__ out)
{
    int t = threadIdx.x;
    if (t >= 2) return;
    int b = t;
    const double* s = sums + b * 12;
    double den = s[5] > 1e-6 ? s[5] : 1e-6;
    double g00 = s[0] / den + 1e-4, g01 = s[1] / den, g02 = s[3] / den;
    double g11 = s[2] / den + 1e-4, g12 = s[4] / den;
    double g22 = s[5] / den + 1e-4;
    double bx0 = s[6] / den, bx1 = s[7] / den, bx2 = s[8] / den;
    double by0 = s[9] / den, by1 = s[10] / den, by2 = s[11] / den;
    double c00 = g11 * g22 - g12 * g12;
    double c01 = g02 * g12 - g01 * g22;
    double c02 = g01 * g12 - g02 * g11;
    double det = g00 * c00 + g01 * c01 + g02 * c02;
    double id = 1.0 / det;
    double i00 = c00 * id, i01 = c01 * id, i02 = c02 * id;
    double i11 = (g00 * g22 - g02 * g02) * id, i12 = (g01 * g02 - g00 * g12) * id;
    double i22 = (g00 * g11 - g01 * g01) * id;
    double a_ = i00 * bx0 + i01 * bx1 + i02 * bx2;
    double b_ = i01 * bx0 + i11 * bx1 + i12 * bx2;
    double c_ = i02 * bx0 + i12 * bx1 + i22 * bx2;
    double d_ = i00 * by0 + i01 * by1 + i02 * by2;
    double e_ = i01 * by0 + i11 * by1 + i12 * by2;
    double f_ = i02 * by0 + i12 * by1 + i22 * by2;
    float* o = out + 24576 + b * 9;
    o[0] = (float)a_; o[1] = (float)b_; o[2] = (float)c_;
    o[3] = (float)d_; o[4] = (float)e_; o[5] = (float)f_;
    o[6] = 0.f; o[7] = 0.f; o[8] = 1.f;
}

extern "C" void kernel_launch(void* const* d_in, const int* in_sizes, int n_in,
                              void* d_out, int out_size, void* d_ws, size_t ws_size,
                              hipStream_t stream) {
    const float* fA = (const float*)d_in[0];
    const float* fB = (const float*)d_in[1];
    const float* pA = (const float*)d_in[2];
    const float* pB = (const float*)d_in[3];
    const float* db = (const float*)d_in[4];
    const float* gw = (const float*)d_in[5];
    const float* tp = (const float*)d_in[6];

    float* ws    = (float*)d_ws;
    float* out   = (float*)d_out;
    float* E0    = ws;
    float* zu    = ws + OFF_ZU;
    float* wv    = ws + OFF_WV;
    float* rn    = ws + OFF_RN;
    float* parts = ws + OFF_PARTS;
    short* pk    = (short*)(ws + OFF_PARTS);   // pack planes live in parts (time-shared)
    float* tkv   = ws + OFF_TKV;
    float* tkp   = ws + OFF_TKP;
    float* dp    = ws + OFF_DP;
    float* geo   = ws + OFF_GEO;
    double* sums = (double*)(ws + OFF_SUM);

    init_kernel<<<33, 256, 0, stream>>>(wv);                 // w = e^0 = 1
    norms_kernel<<<4096, 256, 0, stream>>>(fA, fB, rn);
    pack_kernel<<<1024, 256, 0, stream>>>(fA, fB, pk);
    gemm_mfma<<<dim3(64, 64, 2), 256, 0, stream>>>(pk, rn, tp, E0);

    for (int it = 0; it < 5; it++) {
        sink_fused<<<dim3(256, 1, 2), 256, 0, stream>>>(E0, zu, wv, db, parts);
        sink_vB<<<dim3(65, 1, 2), 256, 0, stream>>>(parts, zu, wv, db);
    }

    topk_kernel<<<2048, 256, 0, stream>>>(E0, zu, wv, pA, pB, tkv, tkp, dp);
    geo_kernel<<<256, 256, 0, stream>>>(dp, geo);
    refine_kernel<<<32, 256, 0, stream>>>(tkv, geo, tkp, gw, tp, out);
    affine_reduce<<<2, 256, 0, stream>>>(pA, out, sums);
    affine_solve<<<1, 64, 0, stream>>>(sums, out);
}